// Round 6
// baseline (22901.999 us; speedup 1.0000x reference)
//
#include <hip/hip_runtime.h>
#include <hip/hip_bf16.h>
#include <math.h>

// Round 6 = round 4/5 resubmit (two infra failures in a row: container fail,
// then broker at capacity — zero bench signal yet on this source).
// Hypothesis under test: d_out decodes as float32.

// ---- problem constants ----
#define BB    16
#define DIMC  256
#define HH    64
#define WWD   64
#define LLEN  256
#define NHEAD 4
#define DH    8
#define INNR  32
#define NTOK  (BB*4*LLEN)     // 16384 rows
#define EPSF  1e-5f

__device__ const int d_IDX[16]  = {0,7,10,13,1,4,11,14,2,5,8,15,3,6,9,12};
__device__ const int d_BACK[16] = {0,4,8,12,5,9,13,1,10,14,2,6,15,3,7,11};

// ---- stage input builder: unfold-gather + residual sums ----
__global__ void k_build_tin(const float* __restrict__ x, float* __restrict__ t,
                            const float* __restrict__ a1, const float* __restrict__ a2,
                            const float* __restrict__ a3, int stage) {
    int row = blockIdx.x;            // (b*4+p)*256 + l
    int c   = threadIdx.x;
    int l   = row & (LLEN - 1);
    int bp  = row >> 8;
    int p   = bp & 3;
    int b   = bp >> 2;
    int kidx = d_IDX[stage*4 + p];
    int hh = ((l >> 4) << 2) + (kidx >> 2);
    int ww = ((l & 15) << 2) + (kidx & 3);
    float v = x[(((size_t)b*DIMC + c)*HH + hh)*WWD + ww];
    size_t o = (size_t)row*DIMC + c;
    if (a1) v += a1[o];
    if (a2) v += a2[o];
    if (a3) v += a3[o];
    t[o] = v;
}

// ---- naive LayerNorm: LDS tree reduction ----
__global__ void k_ln(const float* __restrict__ in, float* __restrict__ out,
                     const float* __restrict__ g, const float* __restrict__ bb) {
    int row = blockIdx.x;
    int c   = threadIdx.x;
    __shared__ float s[256], q[256];
    float v = in[(size_t)row*DIMC + c];
    s[c] = v; q[c] = v*v;
    __syncthreads();
    for (int st = 128; st > 0; st >>= 1) {
        if (c < st) { s[c] += s[c+st]; q[c] += q[c+st]; }
        __syncthreads();
    }
    float m   = s[0] * (1.0f/256.0f);
    float var = q[0] * (1.0f/256.0f) - m*m;
    float r   = rsqrtf(var + EPSF);
    out[(size_t)row*DIMC + c] = (v - m)*r*g[c] + bb[c];
}

// ---- naive GEMM: one thread per output element ----
// flags: 1 = silu epilogue, 2 = residual add into existing C
__global__ void k_gemm_nv(const float* __restrict__ A, const float* __restrict__ Bw,
                          float* __restrict__ C, const float* __restrict__ bias,
                          int N, int K, int flags) {
    int m = blockIdx.x;
    int n = blockIdx.y*256 + threadIdx.x;
    if (n >= N) return;
    float acc = 0.0f;
    const float* ar = A + (size_t)m*K;
    for (int k = 0; k < K; ++k)
        acc += ar[k] * Bw[(size_t)k*N + n];
    if (bias) acc += bias[n];
    if (flags & 1) acc = acc / (1.0f + expf(-acc));
    size_t o = (size_t)m*N + n;
    if (flags & 2) acc += C[o];
    C[o] = acc;
}

// ---- naive attention: two-pass softmax, thread = query row ----
__global__ void k_attention(const float* __restrict__ qkv, float* __restrict__ out) {
    int bh = blockIdx.x;          // (b*4+p)*4 + h
    int h  = bh & 3;
    int bp = bh >> 2;
    int i  = threadIdx.x;         // query row 0..255
    __shared__ float Ks[DH][LLEN], Vs[DH][LLEN];
    const float scale = 0.35355339059327373f;  // 1/sqrt(8)
    size_t base = (size_t)bp * LLEN * 96;
    #pragma unroll
    for (int dd = 0; dd < DH; ++dd) {
        Ks[dd][i] = qkv[base + (size_t)i*96 + 32 + h*8 + dd];
        Vs[dd][i] = qkv[base + (size_t)i*96 + 64 + h*8 + dd];
    }
    float q[DH];
    #pragma unroll
    for (int dd = 0; dd < DH; ++dd)
        q[dd] = qkv[base + (size_t)i*96 + h*8 + dd] * scale;
    __syncthreads();
    float m = -1e30f;
    for (int j = 0; j < LLEN; ++j) {
        float sc = 0.0f;
        #pragma unroll
        for (int dd = 0; dd < DH; ++dd) sc += q[dd]*Ks[dd][j];
        m = fmaxf(m, sc);
    }
    float lsum = 0.0f, acc[DH] = {};
    for (int j = 0; j < LLEN; ++j) {
        float sc = 0.0f;
        #pragma unroll
        for (int dd = 0; dd < DH; ++dd) sc += q[dd]*Ks[dd][j];
        float e = expf(sc - m);
        lsum += e;
        #pragma unroll
        for (int dd = 0; dd < DH; ++dd) acc[dd] += e*Vs[dd][j];
    }
    float inv = 1.0f / lsum;
    #pragma unroll
    for (int dd = 0; dd < DH; ++dd)
        out[((size_t)bp*LLEN + i)*INNR + h*8 + dd] = acc[dd]*inv;
}

// ---- fold with BACK gather ----
__global__ void k_fold(const float* __restrict__ xsb, float* __restrict__ yf) {
    int bc = blockIdx.x;          // b*256 + c
    int c  = bc & 255;
    int b  = bc >> 8;
    for (int idx = threadIdx.x; idx < HH*WWD; idx += 256) {
        int hh = idx >> 6, ww = idx & 63;
        int k  = ((hh & 3) << 2) + (ww & 3);
        int j  = d_BACK[k];
        int l  = ((hh >> 2) << 4) + (ww >> 2);
        size_t src = (size_t)(j >> 2)*4194304 +
                     (((size_t)(b*4 + (j & 3))*LLEN + l)*DIMC + c);
        yf[(size_t)bc*4096 + idx] = xsb[src];
    }
}

// ---- GlobalFilter: per (b,c) 64x64 plane, direct DFT (ortho scales cancel) ----
__global__ void k_gfilter(const float* __restrict__ yf, const float* __restrict__ fw,
                          float* __restrict__ zb) {
    int bc = blockIdx.x;          // b*256 + c
    int c  = bc & 255;
    __shared__ float pr[64*65];
    __shared__ float Fr[33*64], Fi[33*64];
    __shared__ float Gr[33*64], Gi[33*64];
    __shared__ float twc[64], tws[64];
    int tid = threadIdx.x;
    if (tid < 64) {
        float s, co;
        sincosf(6.283185307179586f * (float)tid / 64.0f, &s, &co);
        twc[tid] = co; tws[tid] = s;
    }
    const float* src = yf + (size_t)bc*4096;
    for (int idx = tid; idx < 4096; idx += 256)
        pr[(idx >> 6)*65 + (idx & 63)] = src[idx];
    __syncthreads();
    for (int idx = tid; idx < 33*64; idx += 256) {
        int wf = idx >> 6, hr = idx & 63;
        float sr = 0.0f, si = 0.0f;
        for (int w = 0; w < 64; ++w) {
            float v = pr[hr*65 + w];
            int t = (w*wf) & 63;
            sr += v * twc[t];
            si -= v * tws[t];
        }
        Fr[idx] = sr; Fi[idx] = si;
    }
    __syncthreads();
    for (int idx = tid; idx < 33*64; idx += 256) {
        int wf = idx >> 6, hf = idx & 63;
        float sr = 0.0f, si = 0.0f;
        for (int hr = 0; hr < 64; ++hr) {
            float ar = Fr[wf*64 + hr], ai = Fi[wf*64 + hr];
            int t = (hr*hf) & 63;
            float cr = twc[t], ci = -tws[t];
            sr += ar*cr - ai*ci;
            si += ar*ci + ai*cr;
        }
        const float* wp = fw + (((size_t)hf*33 + wf)*256 + c)*2;
        float wr = wp[0], wi = wp[1];
        Gr[idx] = sr*wr - si*wi;
        Gi[idx] = sr*wi + si*wr;
    }
    __syncthreads();
    for (int idx = tid; idx < 33*64; idx += 256) {
        int wf = idx >> 6, hr = idx & 63;
        float sr = 0.0f, si = 0.0f;
        for (int hf = 0; hf < 64; ++hf) {
            float ar = Gr[wf*64 + hf], ai = Gi[wf*64 + hf];
            int t = (hr*hf) & 63;
            float cr = twc[t], ci = tws[t];
            sr += ar*cr - ai*ci;
            si += ar*ci + ai*cr;
        }
        Fr[idx] = sr; Fi[idx] = si;
    }
    __syncthreads();
    float* dst = zb + (size_t)bc*4096;
    for (int idx = tid; idx < 4096; idx += 256) {
        int hr = idx >> 6, w = idx & 63;
        float s = Fr[0*64 + hr] + ((w & 1) ? -Fr[32*64 + hr] : Fr[32*64 + hr]);
        for (int wf = 1; wf < 32; ++wf) {
            int t = (w*wf) & 63;
            s += 2.0f*(Fr[wf*64 + hr]*twc[t] - Fi[wf*64 + hr]*tws[t]);
        }
        dst[idx] = s * (1.0f/4096.0f);
    }
}

// ---- naive conv3: 1x1 (512->256) + BN + SiLU ----
__global__ void k_conv3(const float* __restrict__ zb, const float* __restrict__ x,
                        const float* __restrict__ w3,
                        const float* __restrict__ g, const float* __restrict__ bb,
                        const float* __restrict__ mm, const float* __restrict__ vv,
                        float* __restrict__ out) {
    int b  = blockIdx.z;
    int co = blockIdx.y;
    int n  = blockIdx.x*256 + threadIdx.x;   // spatial 0..4095
    float acc = 0.0f;
    const float* wr = w3 + (size_t)co*512;
    const float* zp = zb + (size_t)b*256*4096 + n;
    const float* xp = x  + (size_t)b*256*4096 + n;
    for (int ci = 0; ci < 256; ++ci) acc += wr[ci]       * zp[(size_t)ci*4096];
    for (int ci = 0; ci < 256; ++ci) acc += wr[256 + ci] * xp[(size_t)ci*4096];
    float s  = g[co] * rsqrtf(vv[co] + EPSF);
    float bs = bb[co] - mm[co]*s;
    float v  = acc*s + bs;
    v = v / (1.0f + expf(-v));
    out[((size_t)b*256 + co)*4096 + n] = v;
}

// ---- naive conv4: 3x3 (256->256) pad 1 + BN + SiLU -> FLOAT32 output ----
__global__ void k_conv4(const float* __restrict__ in, const float* __restrict__ w4,
                        const float* __restrict__ g, const float* __restrict__ bb,
                        const float* __restrict__ mm, const float* __restrict__ vv,
                        float* __restrict__ out) {
    int b  = blockIdx.z;
    int co = blockIdx.y;
    int hr = blockIdx.x;
    int w  = threadIdx.x;        // 64 threads = 1 row
    float acc = 0.0f;
    const float* inb = in + (size_t)b*256*4096;
    const float* wb  = w4 + (size_t)co*256*9;
    for (int ci = 0; ci < 256; ++ci) {
        const float* ip = inb + (size_t)ci*4096;
        const float* wp = wb + (size_t)ci*9;
        #pragma unroll
        for (int dy = 0; dy < 3; ++dy) {
            int hy = hr + dy - 1;
            if (hy < 0 || hy >= 64) continue;
            #pragma unroll
            for (int dx = 0; dx < 3; ++dx) {
                int wx = w + dx - 1;
                if (wx < 0 || wx >= 64) continue;
                acc += ip[hy*64 + wx] * wp[dy*3 + dx];
            }
        }
    }
    float s  = g[co] * rsqrtf(vv[co] + EPSF);
    float bs = bb[co] - mm[co]*s;
    float v  = acc*s + bs;
    v = v / (1.0f + expf(-v));
    out[(((size_t)b*256 + co)*64 + hr)*64 + w] = v;
}

extern "C" void kernel_launch(void* const* d_in, const int* in_sizes, int n_in,
                              void* d_out, int out_size, void* d_ws, size_t ws_size,
                              hipStream_t stream) {
    const float* x      = (const float*)d_in[0];
    const float* ln1_g  = (const float*)d_in[1];
    const float* ln1_b  = (const float*)d_in[2];
    const float* wqkv   = (const float*)d_in[3];
    const float* wout   = (const float*)d_in[4];
    const float* bout   = (const float*)d_in[5];
    const float* ln2_g  = (const float*)d_in[6];
    const float* ln2_b  = (const float*)d_in[7];
    const float* w1     = (const float*)d_in[8];
    const float* b1     = (const float*)d_in[9];
    const float* w2     = (const float*)d_in[10];
    const float* b2     = (const float*)d_in[11];
    const float* fft_w  = (const float*)d_in[12];
    const float* conv3w = (const float*)d_in[13];
    const float* bn3g   = (const float*)d_in[14];
    const float* bn3b   = (const float*)d_in[15];
    const float* bn3m   = (const float*)d_in[16];
    const float* bn3v   = (const float*)d_in[17];
    const float* conv4w = (const float*)d_in[18];
    const float* bn4g   = (const float*)d_in[19];
    const float* bn4b   = (const float*)d_in[20];
    const float* bn4m   = (const float*)d_in[21];
    const float* bn4v   = (const float*)d_in[22];

    // ---- workspace: exactly 8T floats = 128 MiB ----
    float* ws = (float*)d_ws;
    const size_t T = (size_t)NTOK * DIMC;          // 4,194,304 floats
    float* xs   = ws;                              // [0, 4T)  stage outputs
    float* lnb  = ws + 4*T;                        // [4T, 5T)
    float* qkvb = ws + 5*T;                        // [5T, 5.375T)
    float* attb = qkvb + (size_t)NTOK*96;          // [5.375T, 5.5T)
    float* hbuf = ws + 6*T;                        // [6T, 8T)
    float* yf   = ws + 4*T;                        // alias scratch (dead after stages)
    float* zb   = xs;                              // alias xs (dead after fold)
    float* c3o  = yf;                              // alias yf (dead after gfilter)

    for (int s = 0; s < 4; ++s) {
        float* t = xs + (size_t)s*T;
        k_build_tin<<<NTOK, 256, 0, stream>>>(x, t,
            (s > 0) ? xs : nullptr,
            (s > 1) ? xs + T : nullptr,
            (s > 2) ? xs + 2*T : nullptr, s);
        for (int dep = 0; dep < 2; ++dep) {
            k_ln<<<NTOK, 256, 0, stream>>>(t, lnb, ln1_g + dep*256, ln1_b + dep*256);
            k_gemm_nv<<<dim3(NTOK, 1), 256, 0, stream>>>(lnb, wqkv + (size_t)dep*256*96,
                                                         qkvb, nullptr, 96, 256, 0);
            k_attention<<<BB*4*NHEAD, 256, 0, stream>>>(qkvb, attb);
            k_gemm_nv<<<dim3(NTOK, 1), 256, 0, stream>>>(attb, wout + (size_t)dep*32*256,
                                                         t, bout + dep*256, 256, 32, 2);
            k_ln<<<NTOK, 256, 0, stream>>>(t, lnb, ln2_g + dep*256, ln2_b + dep*256);
            k_gemm_nv<<<dim3(NTOK, 2), 256, 0, stream>>>(lnb, w1 + (size_t)dep*256*512,
                                                         hbuf, b1 + dep*512, 512, 256, 1);
            k_gemm_nv<<<dim3(NTOK, 1), 256, 0, stream>>>(hbuf, w2 + (size_t)dep*512*256,
                                                         t, b2 + dep*256, 256, 512, 2);
        }
    }
    k_fold<<<BB*DIMC, 256, 0, stream>>>(xs, yf);
    k_gfilter<<<BB*DIMC, 256, 0, stream>>>(yf, fft_w, zb);
    k_conv3<<<dim3(16, 256, BB), 256, 0, stream>>>(zb, x, conv3w, bn3g, bn3b, bn3m, bn3v, c3o);
    k_conv4<<<dim3(64, 256, BB), 64, 0, stream>>>(c3o, conv4w, bn4g, bn4b, bn4m, bn4v,
                                                  (float*)d_out);
}

// Round 7
// 4076.663 us; speedup vs baseline: 5.6178x; 5.6178x over previous
//
#include <hip/hip_runtime.h>
#include <hip/hip_bf16.h>
#include <math.h>

// ---- problem constants ----
#define BB    16
#define DIMC  256
#define HH    64
#define WWD   64
#define LLEN  256
#define NHEAD 4
#define DH    8
#define INNR  32
#define NTOK  (BB*4*LLEN)     // 16384 rows
#define EPSF  1e-5f

typedef __bf16 bf16_t;
typedef bf16_t bf16x4 __attribute__((ext_vector_type(4)));
typedef bf16_t bf16x8 __attribute__((ext_vector_type(8)));
typedef float  f32x4  __attribute__((ext_vector_type(4)));

__device__ const int d_IDX[16]  = {0,7,10,13,1,4,11,14,2,5,8,15,3,6,9,12};
__device__ const int d_BACK[16] = {0,4,8,12,5,9,13,1,10,14,2,6,15,3,7,11};

// ---- stage input builder: unfold-gather + residual sums ----
__global__ void k_build_tin(const float* __restrict__ x, float* __restrict__ t,
                            const float* __restrict__ a1, const float* __restrict__ a2,
                            const float* __restrict__ a3, int stage) {
    int row = blockIdx.x;            // (b*4+p)*256 + l
    int c   = threadIdx.x;
    int l   = row & (LLEN - 1);
    int bp  = row >> 8;
    int p   = bp & 3;
    int b   = bp >> 2;
    int kidx = d_IDX[stage*4 + p];
    int hh = ((l >> 4) << 2) + (kidx >> 2);
    int ww = ((l & 15) << 2) + (kidx & 3);
    float v = x[(((size_t)b*DIMC + c)*HH + hh)*WWD + ww];
    size_t o = (size_t)row*DIMC + c;
    if (a1) v += a1[o];
    if (a2) v += a2[o];
    if (a3) v += a3[o];
    t[o] = v;
}

// ---- LayerNorm: LDS tree reduction ----
__global__ void k_ln(const float* __restrict__ in, float* __restrict__ out,
                     const float* __restrict__ g, const float* __restrict__ bb) {
    int row = blockIdx.x;
    int c   = threadIdx.x;
    __shared__ float s[256], q[256];
    float v = in[(size_t)row*DIMC + c];
    s[c] = v; q[c] = v*v;
    __syncthreads();
    for (int st = 128; st > 0; st >>= 1) {
        if (c < st) { s[c] += s[c+st]; q[c] += q[c+st]; }
        __syncthreads();
    }
    float m   = s[0] * (1.0f/256.0f);
    float var = q[0] * (1.0f/256.0f) - m*m;
    float r   = rsqrtf(var + EPSF);
    out[(size_t)row*DIMC + c] = (v - m)*r*g[c] + bb[c];
}

// ===================== MFMA bf16 GEMM =====================
// C[M,N] = A[M,K] @ B[K,N]; A,B fp32 in global, converted to bf16 in staging.
// flags: 1 = silu epilogue, 2 = residual add into existing C
// Tile 128x128, BK=32, 4 waves (each 64x64 = 4x4 frags of 16x16x32).
#define LDK 40   // 32 + 8 pad (keeps 16B align, ~2-way banks)

__global__ __launch_bounds__(256)
void k_gemm_mfma(const float* __restrict__ A, const float* __restrict__ Bw,
                 float* __restrict__ C, const float* __restrict__ bias,
                 int M, int N, int K, int flags) {
    __shared__ bf16_t Al[128][LDK];
    __shared__ bf16_t Bl[128][LDK];   // transposed: [n][k]
    int tid  = threadIdx.x;
    int bm   = blockIdx.y * 128;
    int bn   = blockIdx.x * 128;
    int lane = tid & 63;
    int wv   = tid >> 6;
    int wr   = (wv >> 1) * 64;
    int wc   = (wv & 1) * 64;
    int r16  = lane & 15;
    int krow = (lane >> 4) * 8;
    f32x4 acc[4][4] = {};
    for (int k0 = 0; k0 < K; k0 += 32) {
        #pragma unroll
        for (int i = 0; i < 4; ++i) {           // stage A: 128x32 fp32 -> bf16
            int f = i*256 + tid;
            int m = f >> 3, kq = (f & 7) * 4;
            f32x4 v = *reinterpret_cast<const f32x4*>(A + (size_t)(bm + m)*K + k0 + kq);
            bf16x4 h = { (bf16_t)v.x, (bf16_t)v.y, (bf16_t)v.z, (bf16_t)v.w };
            *reinterpret_cast<bf16x4*>(&Al[m][kq]) = h;
        }
        #pragma unroll
        for (int i = 0; i < 4; ++i) {           // stage B transposed: [n][k]
            int f = i*256 + tid;
            int kk = f >> 5, nq = (f & 31) * 4;
            const float* gp = Bw + (size_t)(k0 + kk)*N + bn + nq;
            #pragma unroll
            for (int j = 0; j < 4; ++j)
                Bl[nq + j][kk] = (bf16_t)((bn + nq + j < N) ? gp[j] : 0.0f);
        }
        __syncthreads();
        bf16x8 af[4], bfr[4];
        #pragma unroll
        for (int mi = 0; mi < 4; ++mi)
            af[mi] = *reinterpret_cast<const bf16x8*>(&Al[wr + mi*16 + r16][krow]);
        #pragma unroll
        for (int ni = 0; ni < 4; ++ni)
            bfr[ni] = *reinterpret_cast<const bf16x8*>(&Bl[wc + ni*16 + r16][krow]);
        #pragma unroll
        for (int mi = 0; mi < 4; ++mi)
            #pragma unroll
            for (int ni = 0; ni < 4; ++ni)
                acc[mi][ni] = __builtin_amdgcn_mfma_f32_16x16x32_bf16(af[mi], bfr[ni], acc[mi][ni], 0, 0, 0);
        __syncthreads();
    }
    int r0 = (lane >> 4) * 4;
    #pragma unroll
    for (int mi = 0; mi < 4; ++mi)
        #pragma unroll
        for (int ni = 0; ni < 4; ++ni) {
            int gcol = bn + wc + ni*16 + r16;
            if (gcol >= N) continue;
            #pragma unroll
            for (int e = 0; e < 4; ++e) {
                int grow = bm + wr + mi*16 + r0 + e;
                float v = acc[mi][ni][e];
                if (bias) v += bias[gcol];
                if (flags & 1) v = v / (1.0f + expf(-v));
                size_t o = (size_t)grow*N + gcol;
                if (flags & 2) v += C[o];
                C[o] = v;
            }
        }
}

// ===================== conv3 as MFMA GEMM =====================
// out[b][co][sp] = BN_SiLU( sum_ci w3[co][ci] * concat(zb,x)[b][ci][sp] )
// M=co(256, 2 blocks), per-b N-tiles of 128 spatial, K=512.
__global__ __launch_bounds__(256)
void k_conv3_mfma(const float* __restrict__ zb, const float* __restrict__ x,
                  const float* __restrict__ w3,
                  const float* __restrict__ g, const float* __restrict__ bb,
                  const float* __restrict__ mm, const float* __restrict__ vv,
                  float* __restrict__ out) {
    __shared__ bf16_t Al[128][LDK];
    __shared__ bf16_t Bl[128][LDK];
    int tid  = threadIdx.x;
    int n0   = blockIdx.x * 128;
    int bm   = blockIdx.y * 128;
    int b    = blockIdx.z;
    int lane = tid & 63;
    int wv   = tid >> 6;
    int wr   = (wv >> 1) * 64;
    int wc   = (wv & 1) * 64;
    int r16  = lane & 15;
    int krow = (lane >> 4) * 8;
    f32x4 acc[4][4] = {};
    for (int k0 = 0; k0 < 512; k0 += 32) {
        #pragma unroll
        for (int i = 0; i < 4; ++i) {           // A = w3[co][ci]
            int f = i*256 + tid;
            int m = f >> 3, kq = (f & 7) * 4;
            f32x4 v = *reinterpret_cast<const f32x4*>(w3 + (size_t)(bm + m)*512 + k0 + kq);
            bf16x4 h = { (bf16_t)v.x, (bf16_t)v.y, (bf16_t)v.z, (bf16_t)v.w };
            *reinterpret_cast<bf16x4*>(&Al[m][kq]) = h;
        }
        #pragma unroll
        for (int i = 0; i < 4; ++i) {           // B = concat(zb,x)[ci][sp]
            int f = i*256 + tid;
            int kk = f >> 5, nq = (f & 31) * 4;
            int ci = k0 + kk;
            const float* gp = (ci < 256) ? (zb + ((size_t)b*256 + ci)*4096 + n0 + nq)
                                         : (x  + ((size_t)b*256 + ci - 256)*4096 + n0 + nq);
            f32x4 v = *reinterpret_cast<const f32x4*>(gp);
            Bl[nq+0][kk] = (bf16_t)v.x; Bl[nq+1][kk] = (bf16_t)v.y;
            Bl[nq+2][kk] = (bf16_t)v.z; Bl[nq+3][kk] = (bf16_t)v.w;
        }
        __syncthreads();
        bf16x8 af[4], bfr[4];
        #pragma unroll
        for (int mi = 0; mi < 4; ++mi)
            af[mi] = *reinterpret_cast<const bf16x8*>(&Al[wr + mi*16 + r16][krow]);
        #pragma unroll
        for (int ni = 0; ni < 4; ++ni)
            bfr[ni] = *reinterpret_cast<const bf16x8*>(&Bl[wc + ni*16 + r16][krow]);
        #pragma unroll
        for (int mi = 0; mi < 4; ++mi)
            #pragma unroll
            for (int ni = 0; ni < 4; ++ni)
                acc[mi][ni] = __builtin_amdgcn_mfma_f32_16x16x32_bf16(af[mi], bfr[ni], acc[mi][ni], 0, 0, 0);
        __syncthreads();
    }
    int r0 = (lane >> 4) * 4;
    #pragma unroll
    for (int mi = 0; mi < 4; ++mi)
        #pragma unroll
        for (int ni = 0; ni < 4; ++ni) {
            int sp = n0 + wc + ni*16 + r16;
            #pragma unroll
            for (int e = 0; e < 4; ++e) {
                int co = bm + wr + mi*16 + r0 + e;
                float s  = g[co] * rsqrtf(vv[co] + EPSF);
                float bs = bb[co] - mm[co]*s;
                float v  = acc[mi][ni][e]*s + bs;
                v = v / (1.0f + expf(-v));
                out[((size_t)b*256 + co)*4096 + sp] = v;
            }
        }
}

// ---- conv4 weight repack: w4t[s][co][ci] = bf16(w4[co][ci][s]) ----
__global__ void k_w4repack(const float* __restrict__ w4, bf16_t* __restrict__ w4t) {
    int idx = blockIdx.x*256 + threadIdx.x;   // 9*256*256 = 589824
    int s = idx >> 16, r = idx & 65535;
    int co = r >> 8, ci = r & 255;
    w4t[idx] = (bf16_t)w4[((size_t)co*256 + ci)*9 + s];
}

// ===================== conv4 as 9-shift MFMA GEMM =====================
// out[b][co][sp] = BN_SiLU( sum_s sum_ci w4t[s][co][ci] * in[b][ci][sp shifted] )
__global__ __launch_bounds__(256)
void k_conv4_mfma(const float* __restrict__ in, const bf16_t* __restrict__ w4t,
                  const float* __restrict__ g, const float* __restrict__ bb,
                  const float* __restrict__ mm, const float* __restrict__ vv,
                  float* __restrict__ out) {
    __shared__ bf16_t Al[128][LDK];
    __shared__ bf16_t Bl[128][LDK];
    int tid  = threadIdx.x;
    int n0   = blockIdx.x * 128;     // spatial tile (2 rows of 64)
    int bm   = blockIdx.y * 128;     // co block
    int b    = blockIdx.z;
    int lane = tid & 63;
    int wv   = tid >> 6;
    int wr   = (wv >> 1) * 64;
    int wc   = (wv & 1) * 64;
    int r16  = lane & 15;
    int krow = (lane >> 4) * 8;
    const float* inb = in + (size_t)b*256*4096;
    f32x4 acc[4][4] = {};
    for (int s9 = 0; s9 < 9; ++s9) {
        int dy = s9/3 - 1, dx = s9%3 - 1;
        for (int k0 = 0; k0 < 256; k0 += 32) {
            #pragma unroll
            for (int i = 0; i < 4; ++i) {       // A = w4t[s9][co][ci] (bf16 direct)
                int f = i*256 + tid;
                int m = f >> 3, kq = (f & 7) * 4;
                *reinterpret_cast<bf16x4*>(&Al[m][kq]) =
                    *reinterpret_cast<const bf16x4*>(w4t + ((size_t)s9*256 + bm + m)*256 + k0 + kq);
            }
            #pragma unroll
            for (int i = 0; i < 4; ++i) {       // B = shifted input, border-masked
                int f = i*256 + tid;
                int kk = f >> 5, nq = (f & 31) * 4;
                int ci = k0 + kk;
                const float* ip = inb + (size_t)ci*4096;
                #pragma unroll
                for (int j = 0; j < 4; ++j) {
                    int sp = n0 + nq + j;
                    int hh = (sp >> 6) + dy, wwx = (sp & 63) + dx;
                    float v = (hh >= 0 && hh < 64 && wwx >= 0 && wwx < 64)
                              ? ip[hh*64 + wwx] : 0.0f;
                    Bl[nq + j][kk] = (bf16_t)v;
                }
            }
            __syncthreads();
            bf16x8 af[4], bfr[4];
            #pragma unroll
            for (int mi = 0; mi < 4; ++mi)
                af[mi] = *reinterpret_cast<const bf16x8*>(&Al[wr + mi*16 + r16][krow]);
            #pragma unroll
            for (int ni = 0; ni < 4; ++ni)
                bfr[ni] = *reinterpret_cast<const bf16x8*>(&Bl[wc + ni*16 + r16][krow]);
            #pragma unroll
            for (int mi = 0; mi < 4; ++mi)
                #pragma unroll
                for (int ni = 0; ni < 4; ++ni)
                    acc[mi][ni] = __builtin_amdgcn_mfma_f32_16x16x32_bf16(af[mi], bfr[ni], acc[mi][ni], 0, 0, 0);
            __syncthreads();
        }
    }
    int r0 = (lane >> 4) * 4;
    #pragma unroll
    for (int mi = 0; mi < 4; ++mi)
        #pragma unroll
        for (int ni = 0; ni < 4; ++ni) {
            int sp = n0 + wc + ni*16 + r16;
            #pragma unroll
            for (int e = 0; e < 4; ++e) {
                int co = bm + wr + mi*16 + r0 + e;
                float s  = g[co] * rsqrtf(vv[co] + EPSF);
                float bs = bb[co] - mm[co]*s;
                float v  = acc[mi][ni][e]*s + bs;
                v = v / (1.0f + expf(-v));
                out[((size_t)b*256 + co)*4096 + sp] = v;
            }
        }
}

// ---- attention: two-pass softmax, thread = query row (fp32, unchanged) ----
__global__ void k_attention(const float* __restrict__ qkv, float* __restrict__ out) {
    int bh = blockIdx.x;
    int h  = bh & 3;
    int bp = bh >> 2;
    int i  = threadIdx.x;
    __shared__ float Ks[DH][LLEN], Vs[DH][LLEN];
    const float scale = 0.35355339059327373f;
    size_t base = (size_t)bp * LLEN * 96;
    #pragma unroll
    for (int dd = 0; dd < DH; ++dd) {
        Ks[dd][i] = qkv[base + (size_t)i*96 + 32 + h*8 + dd];
        Vs[dd][i] = qkv[base + (size_t)i*96 + 64 + h*8 + dd];
    }
    float q[DH];
    #pragma unroll
    for (int dd = 0; dd < DH; ++dd)
        q[dd] = qkv[base + (size_t)i*96 + h*8 + dd] * scale;
    __syncthreads();
    float m = -1e30f;
    for (int j = 0; j < LLEN; ++j) {
        float sc = 0.0f;
        #pragma unroll
        for (int dd = 0; dd < DH; ++dd) sc += q[dd]*Ks[dd][j];
        m = fmaxf(m, sc);
    }
    float lsum = 0.0f, acc[DH] = {};
    for (int j = 0; j < LLEN; ++j) {
        float sc = 0.0f;
        #pragma unroll
        for (int dd = 0; dd < DH; ++dd) sc += q[dd]*Ks[dd][j];
        float e = expf(sc - m);
        lsum += e;
        #pragma unroll
        for (int dd = 0; dd < DH; ++dd) acc[dd] += e*Vs[dd][j];
    }
    float inv = 1.0f / lsum;
    #pragma unroll
    for (int dd = 0; dd < DH; ++dd)
        out[((size_t)bp*LLEN + i)*INNR + h*8 + dd] = acc[dd]*inv;
}

// ---- fold with BACK gather ----
__global__ void k_fold(const float* __restrict__ xsb, float* __restrict__ yf) {
    int bc = blockIdx.x;
    int c  = bc & 255;
    int b  = bc >> 8;
    for (int idx = threadIdx.x; idx < HH*WWD; idx += 256) {
        int hh = idx >> 6, ww = idx & 63;
        int k  = ((hh & 3) << 2) + (ww & 3);
        int j  = d_BACK[k];
        int l  = ((hh >> 2) << 4) + (ww >> 2);
        size_t src = (size_t)(j >> 2)*4194304 +
                     (((size_t)(b*4 + (j & 3))*LLEN + l)*DIMC + c);
        yf[(size_t)bc*4096 + idx] = xsb[src];
    }
}

// ---- GlobalFilter: per (b,c) 64x64 plane, direct DFT (ortho scales cancel) ----
__global__ void k_gfilter(const float* __restrict__ yf, const float* __restrict__ fw,
                          float* __restrict__ zb) {
    int bc = blockIdx.x;
    int c  = bc & 255;
    __shared__ float pr[64*65];
    __shared__ float Fr[33*64], Fi[33*64];
    __shared__ float Gr[33*64], Gi[33*64];
    __shared__ float twc[64], tws[64];
    int tid = threadIdx.x;
    if (tid < 64) {
        float s, co;
        sincosf(6.283185307179586f * (float)tid / 64.0f, &s, &co);
        twc[tid] = co; tws[tid] = s;
    }
    const float* src = yf + (size_t)bc*4096;
    for (int idx = tid; idx < 4096; idx += 256)
        pr[(idx >> 6)*65 + (idx & 63)] = src[idx];
    __syncthreads();
    for (int idx = tid; idx < 33*64; idx += 256) {
        int wf = idx >> 6, hr = idx & 63;
        float sr = 0.0f, si = 0.0f;
        for (int w = 0; w < 64; ++w) {
            float v = pr[hr*65 + w];
            int t = (w*wf) & 63;
            sr += v * twc[t];
            si -= v * tws[t];
        }
        Fr[idx] = sr; Fi[idx] = si;
    }
    __syncthreads();
    for (int idx = tid; idx < 33*64; idx += 256) {
        int wf = idx >> 6, hf = idx & 63;
        float sr = 0.0f, si = 0.0f;
        for (int hr = 0; hr < 64; ++hr) {
            float ar = Fr[wf*64 + hr], ai = Fi[wf*64 + hr];
            int t = (hr*hf) & 63;
            float cr = twc[t], ci = -tws[t];
            sr += ar*cr - ai*ci;
            si += ar*ci + ai*cr;
        }
        const float* wp = fw + (((size_t)hf*33 + wf)*256 + c)*2;
        float wr = wp[0], wi = wp[1];
        Gr[idx] = sr*wr - si*wi;
        Gi[idx] = sr*wi + si*wr;
    }
    __syncthreads();
    for (int idx = tid; idx < 33*64; idx += 256) {
        int wf = idx >> 6, hr = idx & 63;
        float sr = 0.0f, si = 0.0f;
        for (int hf = 0; hf < 64; ++hf) {
            float ar = Gr[wf*64 + hf], ai = Gi[wf*64 + hf];
            int t = (hr*hf) & 63;
            float cr = twc[t], ci = tws[t];
            sr += ar*cr - ai*ci;
            si += ar*ci + ai*cr;
        }
        Fr[idx] = sr; Fi[idx] = si;
    }
    __syncthreads();
    float* dst = zb + (size_t)bc*4096;
    for (int idx = tid; idx < 4096; idx += 256) {
        int hr = idx >> 6, w = idx & 63;
        float s = Fr[0*64 + hr] + ((w & 1) ? -Fr[32*64 + hr] : Fr[32*64 + hr]);
        for (int wf = 1; wf < 32; ++wf) {
            int t = (w*wf) & 63;
            s += 2.0f*(Fr[wf*64 + hr]*twc[t] - Fi[wf*64 + hr]*tws[t]);
        }
        dst[idx] = s * (1.0f/4096.0f);
    }
}

extern "C" void kernel_launch(void* const* d_in, const int* in_sizes, int n_in,
                              void* d_out, int out_size, void* d_ws, size_t ws_size,
                              hipStream_t stream) {
    const float* x      = (const float*)d_in[0];
    const float* ln1_g  = (const float*)d_in[1];
    const float* ln1_b  = (const float*)d_in[2];
    const float* wqkv   = (const float*)d_in[3];
    const float* wout   = (const float*)d_in[4];
    const float* bout   = (const float*)d_in[5];
    const float* ln2_g  = (const float*)d_in[6];
    const float* ln2_b  = (const float*)d_in[7];
    const float* w1     = (const float*)d_in[8];
    const float* b1     = (const float*)d_in[9];
    const float* w2     = (const float*)d_in[10];
    const float* b2     = (const float*)d_in[11];
    const float* fft_w  = (const float*)d_in[12];
    const float* conv3w = (const float*)d_in[13];
    const float* bn3g   = (const float*)d_in[14];
    const float* bn3b   = (const float*)d_in[15];
    const float* bn3m   = (const float*)d_in[16];
    const float* bn3v   = (const float*)d_in[17];
    const float* conv4w = (const float*)d_in[18];
    const float* bn4g   = (const float*)d_in[19];
    const float* bn4b   = (const float*)d_in[20];
    const float* bn4m   = (const float*)d_in[21];
    const float* bn4v   = (const float*)d_in[22];

    // ---- workspace: 8T floats = 128 MiB, two ping-pong regions ----
    float* ws = (float*)d_ws;
    const size_t T = (size_t)NTOK * DIMC;          // 4,194,304 floats
    float* xs   = ws;                              // [0,4T): stages -> zb -> w4t
    float* lnb  = ws + 4*T;
    float* qkvb = ws + 5*T;
    float* attb = qkvb + (size_t)NTOK*96;
    float* hbuf = ws + 6*T;
    float* yf   = ws + 4*T;                        // [4T,8T): fold out -> c3o
    float* zb   = xs;                              // [0,4T)
    float* c3o  = yf;                              // [4T,8T)
    bf16_t* w4t = (bf16_t*)ws;                     // [0, 1.2MB) after conv3

    for (int s = 0; s < 4; ++s) {
        float* t = xs + (size_t)s*T;
        k_build_tin<<<NTOK, 256, 0, stream>>>(x, t,
            (s > 0) ? xs : nullptr,
            (s > 1) ? xs + T : nullptr,
            (s > 2) ? xs + 2*T : nullptr, s);
        for (int dep = 0; dep < 2; ++dep) {
            k_ln<<<NTOK, 256, 0, stream>>>(t, lnb, ln1_g + dep*256, ln1_b + dep*256);
            k_gemm_mfma<<<dim3(1, 128), 256, 0, stream>>>(lnb, wqkv + (size_t)dep*256*96,
                                                          qkvb, nullptr, NTOK, 96, 256, 0);
            k_attention<<<BB*4*NHEAD, 256, 0, stream>>>(qkvb, attb);
            k_gemm_mfma<<<dim3(2, 128), 256, 0, stream>>>(attb, wout + (size_t)dep*32*256,
                                                          t, bout + dep*256, NTOK, 256, 32, 2);
            k_ln<<<NTOK, 256, 0, stream>>>(t, lnb, ln2_g + dep*256, ln2_b + dep*256);
            k_gemm_mfma<<<dim3(4, 128), 256, 0, stream>>>(lnb, w1 + (size_t)dep*256*512,
                                                          hbuf, b1 + dep*512, NTOK, 512, 256, 1);
            k_gemm_mfma<<<dim3(2, 128), 256, 0, stream>>>(hbuf, w2 + (size_t)dep*512*256,
                                                          t, b2 + dep*256, NTOK, 256, 512, 2);
        }
    }
    k_fold<<<BB*DIMC, 256, 0, stream>>>(xs, yf);
    k_gfilter<<<BB*DIMC, 256, 0, stream>>>(yf, fft_w, zb);
    k_conv3_mfma<<<dim3(32, 2, BB), 256, 0, stream>>>(zb, x, conv3w,
                                                      bn3g, bn3b, bn3m, bn3v, c3o);
    k_w4repack<<<2304, 256, 0, stream>>>(conv4w, w4t);   // into dead zb region
    k_conv4_mfma<<<dim3(32, 2, BB), 256, 0, stream>>>(c3o, w4t,
                                                      bn4g, bn4b, bn4m, bn4v, (float*)d_out);
}